// Round 8
// baseline (59.065 us; speedup 1.0000x reference)
//
#include <hip/hip_runtime.h>
#include <cstdint>
#include <cstddef>

#define B_ 32
#define V_ 8
#define S_ 4096
#define E_ 64
#define T_ 1020     // len(arange(0, S-WIN, STEP))
#define TT 32       // tokens per block
#define SLP 200     // e-tile row stride (need >=140 cols)

typedef __bf16 bf16_t;
typedef bf16_t bf16x8 __attribute__((ext_vector_type(8)));
typedef float f32x4 __attribute__((ext_vector_type(4)));

// ---- prep: w2sw swizzled bf16 so a wave's B-fragment is one coalesced 1KB load ----
// elem index i = ((kk*4 + nt)*64 + l)*8 + j  holds  W2[f = kk*32 + (l>>4)*8 + j][n = nt*16 + (l&15)]
__global__ __launch_bounds__(256) void prep_kernel(const float* __restrict__ W2,
                                                   bf16_t* __restrict__ w2sw) {
  const int q = blockIdx.x * 256 + threadIdx.x;      // 8192 quads of 8 elems
  const int l = q & 63, nt = (q >> 6) & 3, kk = q >> 8;
  const int fb = kk * 32 + (l >> 4) * 8;
  const int n = nt * 16 + (l & 15);
  bf16x8 v;
#pragma unroll
  for (int j = 0; j < 8; ++j) v[j] = (bf16_t)W2[(fb + j) * E_ + n];
  *reinterpret_cast<bf16x8*>(w2sw + (size_t)q * 8) = v;
}

// ---- fused kernel (R6 structure), body repeated `rep` times for DIAGNOSTIC amplification ----
// rep is a runtime arg (host passes 8): compiler cannot elide reps; stores are idempotent.
__global__ __launch_bounds__(256, 4) void fused_kernel(const float* __restrict__ x,
                                                       const float* __restrict__ W1,
                                                       const float* __restrict__ b1,
                                                       const bf16_t* __restrict__ w2sw,
                                                       const float* __restrict__ b2,
                                                       float* __restrict__ out,
                                                       int rep) {
  __shared__ bf16_t et[E_ * SLP];   // 25.6 KB
  const int tid = threadIdx.x;
  const int b = blockIdx.y;
  const int t0 = blockIdx.x * TT;
  const int lane = tid & 63;
  const int wv = tid >> 6;              // n-quarter 0..3
  const int l15 = lane & 15;
  const int g = lane >> 4;
  const int dg = tid >> 5;
  const int sg = tid & 31;
  const int s0 = 4 * t0;

  for (int it = 0; it < rep; ++it) {
    // ---- e-build: thread = (d-group of 8, s-lane of 32) x 5 slots ----
    {
      float xv[V_][5];
#pragma unroll
      for (int v = 0; v < V_; ++v) {
#pragma unroll
        for (int k = 0; k < 5; ++k) {
          int s = s0 + sg + 32 * k;
          if (s > S_ - 1) s = S_ - 1;
          xv[v][k] = x[((size_t)(b * V_ + v) << 12) + s];
        }
      }
#pragma unroll
      for (int dd = 0; dd < 8; ++dd) {
        const int d = dg * 8 + dd;
        const float bb = b1[d];
        float acc[5];
#pragma unroll
        for (int k = 0; k < 5; ++k) acc[k] = bb;
#pragma unroll
        for (int v = 0; v < V_; ++v) {
          const float w = W1[v * E_ + d];
#pragma unroll
          for (int k = 0; k < 5; ++k) acc[k] += xv[v][k] * w;
        }
#pragma unroll
        for (int k = 0; k < 5; ++k)
          et[d * SLP + sg + 32 * k] = (bf16_t)floorf(acc[k]);
      }
    }
    __syncthreads();
    // ---- K-loop: A from LDS e-tile, B coalesced-streamed from w2sw ----
    const char* etb = reinterpret_cast<const char*>(et);
    const uint32_t aoff = 400u * (g >> 1) + 8u * l15 + 16u * (g & 1);
    const bf16_t* bptr = w2sw + (((size_t)wv * 64 + lane) << 3);
    const float bv = b2[wv * 16 + l15];
    f32x4 acc0 = {bv, bv, bv, bv};
    f32x4 acc1 = {bv, bv, bv, bv};
#pragma unroll 4
    for (int kk = 0; kk < 32; ++kk) {
      const char* pa = etb + aoff + 800 * kk;
      union { uint64_t q[2]; bf16x8 v; } A0, A1;
      A0.q[0] = *reinterpret_cast<const uint64_t*>(pa);
      A0.q[1] = *reinterpret_cast<const uint64_t*>(pa + 8);
      A1.q[0] = *reinterpret_cast<const uint64_t*>(pa + 128);
      A1.q[1] = *reinterpret_cast<const uint64_t*>(pa + 136);
      const bf16x8 Bf = *reinterpret_cast<const bf16x8*>(bptr + ((size_t)kk << 11));
      acc0 = __builtin_amdgcn_mfma_f32_16x16x32_bf16(A0.v, Bf, acc0, 0, 0, 0);
      acc1 = __builtin_amdgcn_mfma_f32_16x16x32_bf16(A1.v, Bf, acc1, 0, 0, 0);
    }
    // ---- epilogue ----
#pragma unroll
    for (int r = 0; r < 4; ++r) {
      const int t1 = t0 + g * 4 + r;
      if (t1 < T_) out[((size_t)(b * T_ + t1)) * E_ + wv * 16 + l15] = floorf(acc0[r]);
      const int t2 = t0 + 16 + g * 4 + r;
      if (t2 < T_) out[((size_t)(b * T_ + t2)) * E_ + wv * 16 + l15] = floorf(acc1[r]);
    }
    __syncthreads();   // protect et before next rep's e-build overwrites
  }
}

extern "C" void kernel_launch(void* const* d_in, const int* in_sizes, int n_in,
                              void* d_out, int out_size, void* d_ws, size_t ws_size,
                              hipStream_t stream) {
  const float* x  = (const float*)d_in[0];
  const float* W1 = (const float*)d_in[1];
  const float* b1 = (const float*)d_in[2];
  const float* W2 = (const float*)d_in[3];
  const float* b2 = (const float*)d_in[4];
  float* out = (float*)d_out;

  bf16_t* w2sw = (bf16_t*)d_ws;   // 128 KiB swizzled bf16 W2

  hipLaunchKernelGGL(prep_kernel, dim3(32), dim3(256), 0, stream, W2, w2sw);
  hipLaunchKernelGGL(fused_kernel, dim3((T_ + TT - 1) / TT, B_), dim3(256), 0, stream,
                     x, W1, b1, w2sw, b2, out, 8 /* DIAGNOSTIC rep */);
}

// Round 9
// 25.619 us; speedup vs baseline: 2.3055x; 2.3055x over previous
//
#include <hip/hip_runtime.h>
#include <cstdint>
#include <cstddef>

#define B_ 32
#define V_ 8
#define S_ 4096
#define E_ 64
#define T_ 1020     // len(arange(0, S-WIN, STEP))
#define TT 16       // tokens per block (small tile -> 8 blocks/CU -> full occupancy)
#define SLP 80      // e-tile row stride elems (need >=76); 160B row

typedef __bf16 bf16_t;
typedef bf16_t bf16x8 __attribute__((ext_vector_type(8)));
typedef float f32x4 __attribute__((ext_vector_type(4)));

// ---- prep: w2sw swizzled bf16 so a wave's B-fragment is one coalesced 1KB load ----
// elem index i = ((kk*4 + nt)*64 + l)*8 + j  holds  W2[f = kk*32 + (l>>4)*8 + j][n = nt*16 + (l&15)]
__global__ __launch_bounds__(256) void prep_kernel(const float* __restrict__ W2,
                                                   bf16_t* __restrict__ w2sw) {
  const int q = blockIdx.x * 256 + threadIdx.x;      // 8192 quads of 8 elems
  const int l = q & 63, nt = (q >> 6) & 3, kk = q >> 8;
  const int fb = kk * 32 + (l >> 4) * 8;
  const int n = nt * 16 + (l & 15);
  bf16x8 v;
#pragma unroll
  for (int j = 0; j < 8; ++j) v[j] = (bf16_t)W2[(fb + j) * E_ + n];
  *reinterpret_cast<bf16x8*>(w2sw + (size_t)q * 8) = v;
}

// ---- fused: e-tile build (10.2 KB LDS) + barrier-free K-loop; 16 tok x 64 n per block ----
// 4 waves = 4 n-quarters; per wave per kk: 2 ds_read_b64 (A) + 1 dwordx4 (B, L2) + 1 MFMA.
__global__ __launch_bounds__(256, 8) void fused_kernel(const float* __restrict__ x,
                                                       const float* __restrict__ W1,
                                                       const float* __restrict__ b1,
                                                       const bf16_t* __restrict__ w2sw,
                                                       const float* __restrict__ b2,
                                                       float* __restrict__ out) {
  __shared__ bf16_t et[E_ * SLP];   // 10.24 KB
  const int tid = threadIdx.x;
  const int b = blockIdx.y;
  const int t0 = blockIdx.x * TT;
  // ---- e-build: thread = (d-group of 8, s-lane of 32) x 3 slots (s_local 0..75) ----
  {
    const int dg = tid >> 5;
    const int sg = tid & 31;
    const int s0 = 4 * t0;
    float xv[V_][3];
#pragma unroll
    for (int v = 0; v < V_; ++v) {
#pragma unroll
      for (int k = 0; k < 3; ++k) {
        int s = s0 + sg + 32 * k;
        if (s > S_ - 1) s = S_ - 1;     // clamp: only masked-token region affected
        xv[v][k] = x[((size_t)(b * V_ + v) << 12) + s];
      }
    }
    const bool has2 = sg < (76 - 64);   // slot 2 covers s_local 64..75
#pragma unroll
    for (int dd = 0; dd < 8; ++dd) {
      const int d = dg * 8 + dd;
      const float bb = b1[d];
      float acc[3];
#pragma unroll
      for (int k = 0; k < 3; ++k) acc[k] = bb;
#pragma unroll
      for (int v = 0; v < V_; ++v) {
        const float w = W1[v * E_ + d];
#pragma unroll
        for (int k = 0; k < 3; ++k) acc[k] += xv[v][k] * w;
      }
      et[d * SLP + sg]      = (bf16_t)floorf(acc[0]);
      et[d * SLP + sg + 32] = (bf16_t)floorf(acc[1]);
      if (has2) et[d * SLP + sg + 64] = (bf16_t)floorf(acc[2]);
    }
  }
  __syncthreads();
  // ---- K-loop: A from LDS, B coalesced-streamed from w2sw (L2-replicated) ----
  const int lane = tid & 63;
  const int wv = tid >> 6;              // n-quarter 0..3
  const int l15 = lane & 15;
  const int g = lane >> 4;
  const int t = t0 + l15;               // A row m = l15
  const int sl = ((t < T_) ? t : (T_ - 1)) - t0;   // clamped token offset in tile
  const char* etb = reinterpret_cast<const char*>(et);
  // A-frag: d = 2kk + (g>>1) (row 160B), s_local = 4*sl + 8*(g&1)
  const uint32_t aoff = 160u * (g >> 1) + 8u * (uint32_t)sl + 16u * (g & 1);  // +320/kk
  const bf16_t* bptr = w2sw + (((size_t)wv * 64 + lane) << 3);                // +2048/kk
  const float bv = b2[wv * 16 + l15];
  f32x4 acc = {bv, bv, bv, bv};
#pragma unroll 8
  for (int kk = 0; kk < 32; ++kk) {
    const char* pa = etb + aoff + 320u * kk;
    union { uint64_t q[2]; bf16x8 v; } A;
    A.q[0] = *reinterpret_cast<const uint64_t*>(pa);
    A.q[1] = *reinterpret_cast<const uint64_t*>(pa + 8);
    const bf16x8 Bf = *reinterpret_cast<const bf16x8*>(bptr + ((size_t)kk << 11));
    acc = __builtin_amdgcn_mfma_f32_16x16x32_bf16(A.v, Bf, acc, 0, 0, 0);
  }
  // ---- epilogue: D row = g*4 + r (token), col = l15 (n) ----
#pragma unroll
  for (int r = 0; r < 4; ++r) {
    const int tt = t0 + g * 4 + r;
    if (tt < T_) out[((size_t)(b * T_ + tt)) * E_ + wv * 16 + l15] = floorf(acc[r]);
  }
}

extern "C" void kernel_launch(void* const* d_in, const int* in_sizes, int n_in,
                              void* d_out, int out_size, void* d_ws, size_t ws_size,
                              hipStream_t stream) {
  const float* x  = (const float*)d_in[0];
  const float* W1 = (const float*)d_in[1];
  const float* b1 = (const float*)d_in[2];
  const float* W2 = (const float*)d_in[3];
  const float* b2 = (const float*)d_in[4];
  float* out = (float*)d_out;

  bf16_t* w2sw = (bf16_t*)d_ws;   // 128 KiB swizzled bf16 W2

  hipLaunchKernelGGL(prep_kernel, dim3(32), dim3(256), 0, stream, W2, w2sw);
  hipLaunchKernelGGL(fused_kernel, dim3((T_ + TT - 1) / TT, B_), dim3(256), 0, stream,
                     x, W1, b1, w2sw, b2, out);
}

// Round 10
// 20.435 us; speedup vs baseline: 2.8904x; 1.2537x over previous
//
#include <hip/hip_runtime.h>
#include <cstdint>
#include <cstddef>

#define B_ 32
#define V_ 8
#define S_ 4096
#define E_ 64
#define T_ 1020     // len(arange(0, S-WIN, STEP))
#define TT 32       // tokens per block
#define SLP 200     // e-tile row stride (need >=140 cols)

typedef __bf16 bf16_t;
typedef bf16_t bf16x8 __attribute__((ext_vector_type(8)));
typedef float f32x4 __attribute__((ext_vector_type(4)));

// ---- prep: w2sw swizzled bf16 so a wave's B-fragment is one coalesced 1KB load ----
// elem index i = ((kk*4 + nt)*64 + l)*8 + j  holds  W2[f = kk*32 + (l>>4)*8 + j][n = nt*16 + (l&15)]
__global__ __launch_bounds__(256) void prep_kernel(const float* __restrict__ W2,
                                                   bf16_t* __restrict__ w2sw) {
  const int q = blockIdx.x * 256 + threadIdx.x;      // 8192 quads of 8 elems
  const int l = q & 63, nt = (q >> 6) & 3, kk = q >> 8;
  const int fb = kk * 32 + (l >> 4) * 8;
  const int n = nt * 16 + (l & 15);
  bf16x8 v;
#pragma unroll
  for (int j = 0; j < 8; ++j) v[j] = (bf16_t)W2[(fb + j) * E_ + n];
  *reinterpret_cast<bf16x8*>(w2sw + (size_t)q * 8) = v;
}

// ---- fused (R6 base): e-tile build + barrier-free K-loop; latency-chain shortened ----
// Mods vs R6: (1) B[kk<8] preloaded to VGPRs BEFORE e-build (cold-RT overlap);
//             (2) unroll 8 on remaining K-loop; (3) nontemporal out stores (no RFO).
__global__ __launch_bounds__(256, 4) void fused_kernel(const float* __restrict__ x,
                                                       const float* __restrict__ W1,
                                                       const float* __restrict__ b1,
                                                       const bf16_t* __restrict__ w2sw,
                                                       const float* __restrict__ b2,
                                                       float* __restrict__ out) {
  __shared__ bf16_t et[E_ * SLP];   // 25.6 KB
  const int tid = threadIdx.x;
  const int b = blockIdx.y;
  const int t0 = blockIdx.x * TT;
  const int lane = tid & 63;
  const int wv = tid >> 6;              // n-quarter 0..3
  const int l15 = lane & 15;
  const int g = lane >> 4;
  const bf16_t* bptr = w2sw + (((size_t)wv * 64 + lane) << 3);   // +2048 elems per kk

  // ---- issue x loads (e-build inputs) ----
  const int dg = tid >> 5;
  const int sg = tid & 31;
  const int s0 = 4 * t0;
  float xv[V_][5];
#pragma unroll
  for (int v = 0; v < V_; ++v) {
#pragma unroll
    for (int k = 0; k < 5; ++k) {
      int s = s0 + sg + 32 * k;
      if (s > S_ - 1) s = S_ - 1;       // clamp: only masked-token region affected
      xv[v][k] = x[((size_t)(b * V_ + v) << 12) + s];
    }
  }
  // ---- pre-barrier B preload: kk = 0..7 (overlaps cold B round-trip with e-build) ----
  bf16x8 Bpre[8];
#pragma unroll
  for (int kk = 0; kk < 8; ++kk)
    Bpre[kk] = *reinterpret_cast<const bf16x8*>(bptr + ((size_t)kk << 11));
  const float bv = b2[wv * 16 + l15];

  // ---- e-build: thread = (d-group of 8, s-lane of 32) x 5 slots ----
#pragma unroll
  for (int dd = 0; dd < 8; ++dd) {
    const int d = dg * 8 + dd;
    const float bb = b1[d];
    float acc[5];
#pragma unroll
    for (int k = 0; k < 5; ++k) acc[k] = bb;
#pragma unroll
    for (int v = 0; v < V_; ++v) {
      const float w = W1[v * E_ + d];
#pragma unroll
      for (int k = 0; k < 5; ++k) acc[k] += xv[v][k] * w;
    }
#pragma unroll
    for (int k = 0; k < 5; ++k)
      et[d * SLP + sg + 32 * k] = (bf16_t)floorf(acc[k]);
  }
  __syncthreads();

  // ---- K-loop: A from LDS e-tile; B from Bpre (kk<8) then streamed (kk>=8) ----
  const char* etb = reinterpret_cast<const char*>(et);
  const uint32_t aoff = 400u * (g >> 1) + 8u * l15 + 16u * (g & 1);  // +800/kk, +128/mt
  f32x4 acc0 = {bv, bv, bv, bv};
  f32x4 acc1 = {bv, bv, bv, bv};
#pragma unroll
  for (int kk = 0; kk < 8; ++kk) {
    const char* pa = etb + aoff + 800 * kk;
    union { uint64_t q[2]; bf16x8 v; } A0, A1;
    A0.q[0] = *reinterpret_cast<const uint64_t*>(pa);
    A0.q[1] = *reinterpret_cast<const uint64_t*>(pa + 8);
    A1.q[0] = *reinterpret_cast<const uint64_t*>(pa + 128);
    A1.q[1] = *reinterpret_cast<const uint64_t*>(pa + 136);
    acc0 = __builtin_amdgcn_mfma_f32_16x16x32_bf16(A0.v, Bpre[kk], acc0, 0, 0, 0);
    acc1 = __builtin_amdgcn_mfma_f32_16x16x32_bf16(A1.v, Bpre[kk], acc1, 0, 0, 0);
  }
#pragma unroll 8
  for (int kk = 8; kk < 32; ++kk) {
    const char* pa = etb + aoff + 800 * kk;
    union { uint64_t q[2]; bf16x8 v; } A0, A1;
    A0.q[0] = *reinterpret_cast<const uint64_t*>(pa);
    A0.q[1] = *reinterpret_cast<const uint64_t*>(pa + 8);
    A1.q[0] = *reinterpret_cast<const uint64_t*>(pa + 128);
    A1.q[1] = *reinterpret_cast<const uint64_t*>(pa + 136);
    const bf16x8 Bf = *reinterpret_cast<const bf16x8*>(bptr + ((size_t)kk << 11));
    acc0 = __builtin_amdgcn_mfma_f32_16x16x32_bf16(A0.v, Bf, acc0, 0, 0, 0);
    acc1 = __builtin_amdgcn_mfma_f32_16x16x32_bf16(A1.v, Bf, acc1, 0, 0, 0);
  }
  // ---- epilogue: D row = g*4+r (token), col = l15 (n); nontemporal stores ----
#pragma unroll
  for (int r = 0; r < 4; ++r) {
    const int t1 = t0 + g * 4 + r;
    if (t1 < T_)
      __builtin_nontemporal_store(floorf(acc0[r]),
                                  &out[((size_t)(b * T_ + t1)) * E_ + wv * 16 + l15]);
    const int t2 = t0 + 16 + g * 4 + r;
    if (t2 < T_)
      __builtin_nontemporal_store(floorf(acc1[r]),
                                  &out[((size_t)(b * T_ + t2)) * E_ + wv * 16 + l15]);
  }
}

extern "C" void kernel_launch(void* const* d_in, const int* in_sizes, int n_in,
                              void* d_out, int out_size, void* d_ws, size_t ws_size,
                              hipStream_t stream) {
  const float* x  = (const float*)d_in[0];
  const float* W1 = (const float*)d_in[1];
  const float* b1 = (const float*)d_in[2];
  const float* W2 = (const float*)d_in[3];
  const float* b2 = (const float*)d_in[4];
  float* out = (float*)d_out;

  bf16_t* w2sw = (bf16_t*)d_ws;   // 128 KiB swizzled bf16 W2

  hipLaunchKernelGGL(prep_kernel, dim3(32), dim3(256), 0, stream, W2, w2sw);
  hipLaunchKernelGGL(fused_kernel, dim3((T_ + TT - 1) / TT, B_), dim3(256), 0, stream,
                     x, W1, b1, w2sw, b2, out);
}